// Round 1
// baseline (1108.196 us; speedup 1.0000x reference)
//
#include <hip/hip_runtime.h>
#include <math.h>

#define N_NODES 20000
#define N_EDGES 320000
#define ETOT (N_EDGES + N_NODES)
#define HID 16
#define OMEGA 100.0f
#define BETA 0.2f

__device__ __forceinline__ float selu_f(float v) {
    const float a  = 1.6732632423543772f;
    const float sc = 1.0507009873554805f;
    return sc * (v > 0.f ? v : a * expm1f(v));
}

// ---------------------------------------------------------------- edge feats
__global__ __launch_bounds__(256) void edge_feat_kernel(
    const int* __restrict__ ei, const float* __restrict__ pos,
    float4* __restrict__ feat)
{
    int e = blockIdx.x * 256 + threadIdx.x;
    if (e >= ETOT) return;
    int s, d;
    if (e < N_EDGES) { s = ei[e]; d = ei[N_EDGES + e]; }
    else             { s = d = e - N_EDGES; }
    float rx = pos[d * 3 + 0] - pos[s * 3 + 0];
    float ry = pos[d * 3 + 1] - pos[s * 3 + 1];
    float rz = pos[d * 3 + 2] - pos[s * 3 + 2];
    float sq = rx * rx + ry * ry + rz * rz;
    float4 f = make_float4(0.f, 0.f, 0.f, 0.f);
    if (sq > 0.f) {
        float rho = sqrtf(sq);
        float th  = atan2f(ry, rx);
        float ph  = asinf(fminf(fmaxf(rz / rho, -1.f), 1.f));
        const float inv_pi = 0.31830988618379067f;
        f = make_float4(rho, th * inv_pi, ph * inv_pi, 0.f);
    }
    feat[e] = f;
}

// ---------------------------------------------------------------- x -> xcat
__global__ __launch_bounds__(256) void copy_x_kernel(
    const float* __restrict__ x, float* __restrict__ xcat)
{
    int i = blockIdx.x * 256 + threadIdx.x;
    if (i >= N_NODES * 16) return;
    int n = i >> 4, c = i & 15;
    xcat[n * 32 + c] = x[i];
}

// ---------------------------------------------------------------- conv edge
template<int IN, int OUT>
__global__ __launch_bounds__(256) void conv_edge_kernel(
    const int* __restrict__ ei, const float4* __restrict__ feat,
    const float* __restrict__ xcat,
    const float* __restrict__ w0, const float* __restrict__ b0,
    const float* __restrict__ w1, const float* __restrict__ b1,
    const float* __restrict__ w2, const float* __restrict__ b2,
    const float* __restrict__ wl, const float* __restrict__ bl,
    float* __restrict__ acc)
{
    int e = blockIdx.x * 256 + threadIdx.x;
    if (e >= ETOT) return;
    int s, d;
    if (e < N_EDGES) { s = ei[e]; d = ei[N_EDGES + e]; }
    else             { s = d = e - N_EDGES; }

    float4 f = feat[e];

    // base[h] = b0[h] + f . w0[h,0:3];  co[h] = w0[h,3]
    float base[HID], co[HID];
#pragma unroll
    for (int h = 0; h < HID; h++) {
        base[h] = b0[h] + f.x * w0[h * 4 + 0] + f.y * w0[h * 4 + 1] + f.z * w0[h * 4 + 2];
        co[h]   = w0[h * 4 + 3];
    }

    // t[h] = sum_i xj[i] * wl[i,h];   blx = sum_i xj[i]*bl[i]
    float t[HID];
#pragma unroll
    for (int h = 0; h < HID; h++) t[h] = 0.f;
    float blx = 0.f;
    const float4* xr = (const float4*)(xcat + s * 32);
#pragma unroll
    for (int i4 = 0; i4 < IN / 4; i4++) {
        float4 xv = xr[i4];
        blx += bl[i4 * 4 + 0] * xv.x + bl[i4 * 4 + 1] * xv.y
             + bl[i4 * 4 + 2] * xv.z + bl[i4 * 4 + 3] * xv.w;
#pragma unroll
        for (int h = 0; h < HID; h++) {
            t[h] += wl[(i4 * 4 + 0) * HID + h] * xv.x
                  + wl[(i4 * 4 + 1) * HID + h] * xv.y
                  + wl[(i4 * 4 + 2) * HID + h] * xv.z
                  + wl[(i4 * 4 + 3) * HID + h] * xv.w;
        }
    }

#pragma unroll 1
    for (int o = 0; o < OUT; o++) {
        float oc = (float)o;
        float h0[HID], h1[HID];
#pragma unroll
        for (int h = 0; h < HID; h++)
            h0[h] = __sinf(OMEGA * (base[h] + oc * co[h]));
#pragma unroll
        for (int g = 0; g < HID; g++) {
            float sa = b1[g];
#pragma unroll
            for (int h = 0; h < HID; h++) sa += h0[h] * w1[g * HID + h];
            h1[g] = __sinf(OMEGA * sa);
        }
        float m = blx;
#pragma unroll
        for (int g = 0; g < HID; g++) {
            float sa = b2[g];
#pragma unroll
            for (int h = 0; h < HID; h++) sa += h1[h] * w2[g * HID + h];
            m += __sinf(OMEGA * sa) * t[g];
        }
        atomicAdd(&acc[d * OUT + o], m);
    }
}

// ---------------------------------------------------------------- finishers
template<int OUT>
__global__ __launch_bounds__(256) void finish_mid_kernel(
    const float* __restrict__ acc, const float* __restrict__ bias,
    float* __restrict__ xcat, int coloff)
{
    int i = blockIdx.x * 256 + threadIdx.x;
    if (i >= N_NODES * OUT) return;
    int n = i / OUT, o = i % OUT;
    xcat[n * 32 + coloff + o] = selu_f(acc[i] + bias[o]);
}

__global__ __launch_bounds__(256) void finish_out_kernel(
    const float* __restrict__ acc, const float* __restrict__ bias,
    const float* __restrict__ x, float* __restrict__ out)
{
    int i = blockIdx.x * 256 + threadIdx.x;
    if (i >= N_NODES * 16) return;
    int c = i & 15;
    out[i] = x[i] + BETA * selu_f(acc[i] + bias[c]);
}

// ---------------------------------------------------------------- launch
extern "C" void kernel_launch(void* const* d_in, const int* in_sizes, int n_in,
                              void* d_out, int out_size, void* d_ws, size_t ws_size,
                              hipStream_t stream)
{
    const float* x   = (const float*)d_in[0];
    const int*   ei  = (const int*)d_in[1];
    const float* pos = (const float*)d_in[2];

    // conv weight pointer bundles: 9 arrays per conv starting at index 3
    const float* W[27];
    for (int i = 0; i < 27; i++) W[i] = (const float*)d_in[3 + i];
    // per conv ci (0-based): w0=W[9c+0] b0=+1 w1=+2 b1=+3 w2=+4 b2=+5 wl=+6 bl=+7 bias=+8

    float* ws    = (float*)d_ws;
    float4* feat = (float4*)ws;                    // ETOT*4 floats
    float* xcat  = ws + (size_t)ETOT * 4;          // N*32
    float* acc1  = xcat + (size_t)N_NODES * 32;    // N*8
    float* acc2  = acc1 + (size_t)N_NODES * 8;     // N*8
    float* acc3  = acc2 + (size_t)N_NODES * 8;     // N*16
    float* out   = (float*)d_out;

    // zero all three accumulators (contiguous N*32 floats)
    hipMemsetAsync(acc1, 0, (size_t)N_NODES * 32 * sizeof(float), stream);

    dim3 blk(256);
    dim3 ge((ETOT + 255) / 256);
    dim3 gx((N_NODES * 16 + 255) / 256);
    dim3 g8((N_NODES * 8 + 255) / 256);

    edge_feat_kernel<<<ge, blk, 0, stream>>>(ei, pos, feat);
    copy_x_kernel<<<gx, blk, 0, stream>>>(x, xcat);

    conv_edge_kernel<16, 8><<<ge, blk, 0, stream>>>(ei, feat, xcat,
        W[0], W[1], W[2], W[3], W[4], W[5], W[6], W[7], acc1);
    finish_mid_kernel<8><<<g8, blk, 0, stream>>>(acc1, W[8], xcat, 16);

    conv_edge_kernel<24, 8><<<ge, blk, 0, stream>>>(ei, feat, xcat,
        W[9], W[10], W[11], W[12], W[13], W[14], W[15], W[16], acc2);
    finish_mid_kernel<8><<<g8, blk, 0, stream>>>(acc2, W[17], xcat, 24);

    conv_edge_kernel<32, 16><<<ge, blk, 0, stream>>>(ei, feat, xcat,
        W[18], W[19], W[20], W[21], W[22], W[23], W[24], W[25], acc3);
    finish_out_kernel<<<gx, blk, 0, stream>>>(acc3, W[26], x, out);
}